// Round 7
// baseline (245.179 us; speedup 1.0000x reference)
//
#include <hip/hip_runtime.h>

// B=8, Cin=Cout=32, H=W=256, K=5. Adaptive bins: start (k*256)/5 = {0,51,102,153,204},
// all length 52 (bins overlap by 1 row/col).
// Pooling is linear: filt_raw[b,o,k,l] = sum_i W[o,i]*xpool_raw[b,i,k,l] + 2704*bias[o]
// so we pool x (tiny) instead of feat; the 1x1 conv is a pure streaming channel mix.
//
// Round-7 structure: ONE merged launch does conv (even blocks) + pool (odd blocks)
// concurrently -- both only read x, and conv alone runs at ~3.1 of ~6.3 TB/s, so
// pool's 67 MB rides in the spare bandwidth instead of serializing afterward.
// Pool writes per-strip partials (no atomics -> no memset dispatch); dw sums them.

#define CIN 32
#define COUT 32
#define HW 256
#define PLANE (HW * HW)
#define BATCH 8
#define KF 5
#define BIN 52

// ---------------- K0: merged 1x1 conv + x-pool partials ----------------
// even blk -> conv: block = one (b,row); thread = one pixel; scalar acc[32]
//   (non-rematerializable -> allocator keeps it live; R6 proof: VGPR=36, zero spill).
// odd blk  -> pool: block = one (plane, 32-row strip); per-strip bin partial sums
//   written non-atomically to xpool_part[plane][strip][25].
__global__ __launch_bounds__(256) void conv_pool_kernel(const float* __restrict__ x,
                                                        const float* __restrict__ Wm,
                                                        const float* __restrict__ bias,
                                                        float* __restrict__ feat,
                                                        float* __restrict__ xpool_part) {
    int blk = blockIdx.x;
    int t   = threadIdx.x;

    __shared__ float plds[KF][HW + 1];     // pool scratch only (5.1 KB)

    if (blk & 1) {
        // ---- pool path: 2048 blocks ----
        int pb    = blk >> 1;          // 0..2047
        int s     = pb & 7;            // row strip 0..7
        int plane = pb >> 3;           // b*32+i, 0..255
        int gy0   = s * 32;

        const float* xp = x + (size_t)plane * PLANE + (size_t)gy0 * HW + t;
        float acc[KF] = {0.f, 0.f, 0.f, 0.f, 0.f};
#pragma unroll
        for (int r = 0; r < 32; ++r) {
            float v  = xp[(size_t)r * HW];
            int   gy = gy0 + r;
#pragma unroll
            for (int k = 0; k < KF; ++k) {            // row-bin membership (bins overlap by 1)
                const int sk = (k * HW) / KF;
                if (gy >= sk && gy < sk + BIN) acc[k] += v;
            }
        }
#pragma unroll
        for (int k = 0; k < KF; ++k) plds[k][t] = acc[k];
        __syncthreads();

        if (t < KF * KF) {                            // 25 workers: (row-bin kk, col-bin ll)
            int kk = t / KF, ll = t - kk * KF;
            int sl = (ll * HW) / KF;
            float ssum = 0.f;
#pragma unroll 4
            for (int w = 0; w < BIN; ++w) ssum += plds[kk][sl + w];
            xpool_part[(size_t)plane * 200 + s * 25 + t] = ssum;   // non-atomic partial
        }
    } else {
        // ---- conv path: 2048 blocks ----
        int cb  = blk >> 1;            // b*256 + row
        int b   = cb >> 8;
        int row = cb & 255;

        const float* xb = x + (size_t)b * CIN * PLANE + (size_t)row * HW + t;
        float*       fb = feat + (size_t)b * COUT * PLANE + (size_t)row * HW + t;

        float acc[COUT];
#pragma unroll
        for (int o = 0; o < COUT; ++o) acc[o] = bias[o];

#pragma unroll
        for (int i = 0; i < CIN; ++i) {
            float xv = xb[(size_t)i * PLANE];        // 4B/lane, 256B/wave coalesced
#pragma unroll
            for (int o = 0; o < COUT; ++o)
                acc[o] += Wm[o * CIN + i] * xv;      // thread-uniform weight -> scalar pipe
        }

#pragma unroll
        for (int o = 0; o < COUT; ++o)
            fb[(size_t)o * PLANE] = acc[o];
    }
}

// ---------------- K1: depthwise 5x5, 16-row x 256-col strips, register sliding window ----
// filt[k][l] = (sum_i W[o,i] * (sum_s xpool_part[b*32+i][s][kl]) + 2704*bias[o]) / 2704
#define RS 16      // output rows per strip
#define LROW 264   // LDS row stride (floats); interior col x at [lr*LROW + 4 + x]
__global__ __launch_bounds__(256, 6) void dwconv_kernel(const float* __restrict__ feat,
                                                        const float* __restrict__ xpool_part,
                                                        const float* __restrict__ Wm,
                                                        const float* __restrict__ bias,
                                                        float* __restrict__ out) {
    int bo    = blockIdx.y;            // 0..255  (b*32+o)
    int b     = bo >> 5;
    int o     = bo & 31;
    int strip = blockIdx.x;            // 0..15
    int gy0   = strip * RS;
    int t     = threadIdx.x;

    __shared__ __align__(16) float s[(RS + 4) * LROW];
    __shared__ float sfilt[25];

    if (t < 25) {
        float accf = bias[o] * 2704.0f;
        const float* xp = xpool_part + (size_t)b * CIN * 200 + t;
#pragma unroll
        for (int i = 0; i < CIN; ++i) {
            float w = Wm[o * CIN + i];
            float p = 0.f;
#pragma unroll
            for (int s2 = 0; s2 < 8; ++s2) p += xp[i * 200 + s2 * 25];  // L2-resident (205KB)
            accf += w * p;
        }
        sfilt[t] = accf * (1.0f / 2704.0f);
    }
    // zero the 2-col pads (LDS idx 2,3 and 260,261) on each of RS+4 rows
    if (t < (RS + 4) * 4) {
        int lr = t >> 2, e = t & 3;
        int ci = (e < 2) ? (2 + e) : (258 + e);
        s[lr * LROW + ci] = 0.f;
    }

    const float* fb = feat + (size_t)bo * PLANE;
#pragma unroll
    for (int j = 0; j < 5; ++j) {          // (RS+4) rows x 64 float4 = 1280 / 256 threads
        int idx = t + 256 * j;
        int lr  = idx >> 6;
        int cx  = (idx & 63) * 4;
        int gy  = gy0 - 2 + lr;
        float4 v = {0.f, 0.f, 0.f, 0.f};
        if ((unsigned)gy < (unsigned)HW) v = *(const float4*)(fb + (size_t)gy * HW + cx);
        *(float4*)(&s[lr * LROW + 4 + cx]) = v;
    }
    __syncthreads();

    float fw[25];
#pragma unroll
    for (int j = 0; j < 25; ++j) fw[j] = sfilt[j];   // LDS broadcast once

    int c = t;   // output column
    float w0[5], w1[5], w2[5], w3[5], w4[5];
#pragma unroll
    for (int j = 0; j < 5; ++j) {
        w0[j] = s[0 * LROW + 2 + c + j];
        w1[j] = s[1 * LROW + 2 + c + j];
        w2[j] = s[2 * LROW + 2 + c + j];
        w3[j] = s[3 * LROW + 2 + c + j];
    }
    float* ob = out + (size_t)bo * PLANE + (size_t)gy0 * HW + c;
#pragma unroll
    for (int r = 0; r < RS; ++r) {
#pragma unroll
        for (int j = 0; j < 5; ++j) w4[j] = s[(r + 4) * LROW + 2 + c + j];
        float acc = 0.f;
#pragma unroll
        for (int j = 0; j < 5; ++j) {
            acc += fw[0 * 5 + j] * w0[j];
            acc += fw[1 * 5 + j] * w1[j];
            acc += fw[2 * 5 + j] * w2[j];
            acc += fw[3 * 5 + j] * w3[j];
            acc += fw[4 * 5 + j] * w4[j];
        }
        ob[(size_t)r * HW] = acc;
#pragma unroll
        for (int j = 0; j < 5; ++j) {      // renamed away under full unroll
            w0[j] = w1[j]; w1[j] = w2[j]; w2[j] = w3[j]; w3[j] = w4[j];
        }
    }
}

extern "C" void kernel_launch(void* const* d_in, const int* in_sizes, int n_in,
                              void* d_out, int out_size, void* d_ws, size_t ws_size,
                              hipStream_t stream) {
    const float* x      = (const float*)d_in[0];
    const float* conv_w = (const float*)d_in[1];
    const float* conv_b = (const float*)d_in[2];
    float* out = (float*)d_out;

    float* feat       = (float*)d_ws;                        // 64 MiB
    float* xpool_part = feat + (size_t)BATCH * COUT * PLANE; // 256 planes x 8 strips x 25

    conv_pool_kernel<<<dim3(4096), dim3(256), 0, stream>>>(x, conv_w, conv_b, feat, xpool_part);
    dwconv_kernel<<<dim3(HW / RS, BATCH * COUT), dim3(256), 0, stream>>>(feat, xpool_part, conv_w, conv_b, out);
}

// Round 8
// 166.802 us; speedup vs baseline: 1.4699x; 1.4699x over previous
//
#include <hip/hip_runtime.h>

// B=8, Cin=Cout=32, H=W=256, K=5. Adaptive bins: start (k*256)/5 = {0,51,102,153,204},
// all length 52 (bins overlap by 1 row/col).
// Pooling is linear: filt[b,o,k,l] = (sum_i W[o,i]*xpool[b,i,k,l] + 2704*bias[o])/2704
// so we pool x (tiny) instead of feat; the 1x1 conv is a pure streaming channel mix.
//
// R8 structure: one merged launch, RANGE-split (blocks 0..2047 conv, 2048..4095 pool).
// R7's parity split (blk&1) put all conv blocks on half the XCDs (round-robin dispatch)
// -> conv ran on half the machine (~80us). Range split spreads both over all XCDs.
// dw: no-LDS register sliding window; horizontal taps served by L1/L2 predicated loads.

#define CIN 32
#define COUT 32
#define HW 256
#define PLANE (HW * HW)
#define BATCH 8
#define KF 5
#define BIN 52

// ---------------- K0: merged 1x1 conv (blocks 0..2047) + x-pool (blocks 2048..4095) ----
// conv: block = one (b,row); thread = one pixel; scalar acc[32] (non-rematerializable ->
//       allocator keeps it live; R6 proof: VGPR=36, zero spill, 43.4us standalone).
// pool: block = one (plane, 32-row strip); LDS column partials; atomicAdd into xpool
//       (xpool memset'd before launch; 2048*25 atomics total - negligible).
__global__ __launch_bounds__(256) void conv_pool_kernel(const float* __restrict__ x,
                                                        const float* __restrict__ Wm,
                                                        const float* __restrict__ bias,
                                                        float* __restrict__ feat,
                                                        float* __restrict__ xpool) {
    int blk = blockIdx.x;
    int t   = threadIdx.x;

    __shared__ float plds[KF][HW + 1];     // pool scratch only (5.1 KB)

    if (blk < 2048) {
        // ---- conv path ----
        int b   = blk >> 8;
        int row = blk & 255;

        const float* xb = x + (size_t)b * CIN * PLANE + (size_t)row * HW + t;
        float*       fb = feat + (size_t)b * COUT * PLANE + (size_t)row * HW + t;

        float acc[COUT];
#pragma unroll
        for (int o = 0; o < COUT; ++o) acc[o] = bias[o];

#pragma unroll
        for (int i = 0; i < CIN; ++i) {
            float xv = xb[(size_t)i * PLANE];        // 4B/lane, 256B/wave coalesced
#pragma unroll
            for (int o = 0; o < COUT; ++o)
                acc[o] += Wm[o * CIN + i] * xv;      // thread-uniform weight -> scalar pipe
        }

#pragma unroll
        for (int o = 0; o < COUT; ++o)
            fb[(size_t)o * PLANE] = acc[o];
    } else {
        // ---- pool path ----
        int pb    = blk - 2048;        // 0..2047
        int s     = pb & 7;            // row strip 0..7
        int plane = pb >> 3;           // b*32+i, 0..255
        int gy0   = s * 32;

        const float* xp = x + (size_t)plane * PLANE + (size_t)gy0 * HW + t;
        float acc[KF] = {0.f, 0.f, 0.f, 0.f, 0.f};
#pragma unroll
        for (int r = 0; r < 32; ++r) {
            float v  = xp[(size_t)r * HW];
            int   gy = gy0 + r;
#pragma unroll
            for (int k = 0; k < KF; ++k) {            // row-bin membership (bins overlap by 1)
                const int sk = (k * HW) / KF;
                if (gy >= sk && gy < sk + BIN) acc[k] += v;
            }
        }
#pragma unroll
        for (int k = 0; k < KF; ++k) plds[k][t] = acc[k];
        __syncthreads();

        if (t < KF * KF) {                            // 25 workers: (row-bin kk, col-bin ll)
            int kk = t / KF, ll = t - kk * KF;
            int sl = (ll * HW) / KF;
            float ssum = 0.f;
#pragma unroll 4
            for (int w = 0; w < BIN; ++w) ssum += plds[kk][sl + w];
            atomicAdd(&xpool[plane * 25 + t], ssum);
        }
    }
}

// ---------------- K1: depthwise 5x5, no-LDS register sliding window ----------------
// Block = (bo, 32-row strip); thread = one output column. Vertical reuse in the
// w0..w4 shift registers; horizontal 5-tap reuse served by L1/L2 (feat strip is
// 20KB, L1-resident; predicated loads handle borders). No staging, no syncthreads
// after prologue, no LDS cap on occupancy (R7 measured the LDS version latency-bound:
// VALUBusy 13%, 946 GB/s). Prologue = 32 L2 loads on t<25 (R6-proven cheap).
__global__ __launch_bounds__(256) void dwconv_kernel(const float* __restrict__ feat,
                                                     const float* __restrict__ xpool,
                                                     const float* __restrict__ Wm,
                                                     const float* __restrict__ bias,
                                                     float* __restrict__ out) {
    int bo    = blockIdx.y;            // 0..255  (b*32+o)
    int b     = bo >> 5;
    int o     = bo & 31;
    int strip = blockIdx.x;            // 0..7
    int gy0   = strip * 32;
    int t     = threadIdx.x;

    __shared__ float sfilt[25];
    if (t < 25) {
        float accf = bias[o] * 2704.0f;
        const float* xp = xpool + (size_t)b * CIN * 25 + t;
#pragma unroll
        for (int i = 0; i < CIN; ++i) accf += Wm[o * CIN + i] * xp[i * 25];  // 32 L2 loads
        sfilt[t] = accf * (1.0f / 2704.0f);
    }
    __syncthreads();

    float fw[25];
#pragma unroll
    for (int j = 0; j < 25; ++j) fw[j] = sfilt[j];   // LDS broadcast once

    const float* fb = feat + (size_t)bo * PLANE;
    int c = t;

    bool cv[5];
#pragma unroll
    for (int j = 0; j < 5; ++j) cv[j] = (unsigned)(c + j - 2) < (unsigned)HW;

    float w0[5], w1[5], w2[5], w3[5], w4[5];
#pragma unroll
    for (int j = 0; j < 5; ++j) {
        int cc = c + j - 2;
        w0[j] = (cv[j] && gy0 - 2 >= 0) ? fb[(size_t)(gy0 - 2) * HW + cc] : 0.f;
        w1[j] = (cv[j] && gy0 - 1 >= 0) ? fb[(size_t)(gy0 - 1) * HW + cc] : 0.f;
        w2[j] =  cv[j]                  ? fb[(size_t)(gy0    ) * HW + cc] : 0.f;
        w3[j] =  cv[j]                  ? fb[(size_t)(gy0 + 1) * HW + cc] : 0.f;
    }

    float* ob = out + (size_t)bo * PLANE + (size_t)gy0 * HW + c;
#pragma unroll
    for (int r = 0; r < 32; ++r) {
        int  gy = gy0 + r + 2;
        bool rv = gy < HW;
#pragma unroll
        for (int j = 0; j < 5; ++j) {
            int cc = c + j - 2;
            w4[j] = (rv && cv[j]) ? fb[(size_t)gy * HW + cc] : 0.f;
        }
        float acc = 0.f;
#pragma unroll
        for (int j = 0; j < 5; ++j) {
            acc += fw[0 * 5 + j] * w0[j];
            acc += fw[1 * 5 + j] * w1[j];
            acc += fw[2 * 5 + j] * w2[j];
            acc += fw[3 * 5 + j] * w3[j];
            acc += fw[4 * 5 + j] * w4[j];
        }
        ob[(size_t)r * HW] = acc;
#pragma unroll
        for (int j = 0; j < 5; ++j) {      // renamed away under full unroll
            w0[j] = w1[j]; w1[j] = w2[j]; w2[j] = w3[j]; w3[j] = w4[j];
        }
    }
}

extern "C" void kernel_launch(void* const* d_in, const int* in_sizes, int n_in,
                              void* d_out, int out_size, void* d_ws, size_t ws_size,
                              hipStream_t stream) {
    const float* x      = (const float*)d_in[0];
    const float* conv_w = (const float*)d_in[1];
    const float* conv_b = (const float*)d_in[2];
    float* out = (float*)d_out;

    float* feat  = (float*)d_ws;                           // 64 MiB
    float* xpool = feat + (size_t)BATCH * COUT * PLANE;    // 8*32*25 floats (raw x bin sums)

    hipMemsetAsync(xpool, 0, BATCH * CIN * 25 * sizeof(float), stream);
    conv_pool_kernel<<<dim3(4096), dim3(256), 0, stream>>>(x, conv_w, conv_b, feat, xpool);
    dwconv_kernel<<<dim3(8, BATCH * COUT), dim3(256), 0, stream>>>(feat, xpool, conv_w, conv_b, out);
}